// Round 1
// baseline (938.352 us; speedup 1.0000x reference)
//
#include <hip/hip_runtime.h>
#include <hip/hip_bf16.h>

typedef __bf16 v8bf __attribute__((ext_vector_type(8)));
typedef __bf16 v4bf __attribute__((ext_vector_type(4)));
typedef float  v4f  __attribute__((ext_vector_type(4)));

#define NMEM 262144
#define CFD  256       // per-feature dim (indiv / collab halves)
#define NSEA 8192

// ---------------- workspace layout (bytes) ----------------
// T1  = Wo@Wv            f32 [512][512]   @ 0          (1048576)
// W3  = Wfc@T1           f32 [256][512]   @ 1048576    (524288)
// bc  = Wo@bv + bo       f32 [512]        @ 1572864    (2048)
// b3  = Wfc@bc + bfc     f32 [256]        @ 1574912    (1024)
// Bp  = W3 packed bf16 MFMA B-frags       @ 1575936    (262144)
// sums   f32 [8192]                       @ 1838080    (32768)
// counts f32 [8192]                       @ 1870848    (32768)

// ---------------- precompute kernels ----------------

__global__ void gemm_nn(const float* __restrict__ A, const float* __restrict__ B,
                        float* __restrict__ C, int M, int Nn, int K) {
  __shared__ float As[16][17];
  __shared__ float Bs[16][17];
  const int tx = threadIdx.x, ty = threadIdx.y;
  const int row = blockIdx.y * 16 + ty;
  const int col = blockIdx.x * 16 + tx;
  float acc = 0.f;
  for (int kk = 0; kk < K; kk += 16) {
    As[ty][tx] = A[row * K + kk + tx];
    Bs[ty][tx] = B[(kk + ty) * Nn + col];
    __syncthreads();
#pragma unroll
    for (int t = 0; t < 16; ++t) acc += As[ty][t] * Bs[t][tx];
    __syncthreads();
  }
  C[row * Nn + col] = acc;
}

__global__ void bias_dot(const float* __restrict__ W, const float* __restrict__ x,
                         const float* __restrict__ b, float* __restrict__ o, int K) {
  const int i = blockIdx.x, L = threadIdx.x;  // 64 threads/block
  const float* row = W + (size_t)i * K;
  float s = 0.f;
  for (int k = L; k < K; k += 64) s += row[k] * x[k];
#pragma unroll
  for (int m = 32; m; m >>= 1) s += __shfl_xor(s, m, 64);
  if (L == 0) o[i] = s + b[i];
}

// Pack W3[256][512] (row-major f32) into bf16 MFMA B fragments:
// Bp[nt][kc][lane][j] = W3[nt*16 + (lane&15)][kc*32 + (lane>>4)*8 + j]
__global__ void pack_b(const float* __restrict__ W3, __bf16* __restrict__ Bp) {
  const int t = blockIdx.x * 256 + threadIdx.x;   // 16384 threads total
  const int L = t & 63, kc = (t >> 6) & 15, nt = t >> 10;
  const int n = nt * 16 + (L & 15);
  const int k = kc * 32 + ((L >> 4) << 3);
  const float* src = W3 + n * 512 + k;
  __bf16* dst = Bp + (size_t)t * 8;
#pragma unroll
  for (int j = 0; j < 8; ++j) dst[j] = (__bf16)src[j];
}

// ---------------- fused main kernel ----------------
// Block: 256 threads (4 waves), 64 members/block (16 per wave).
// Phase A: walk-attention alphas via wave dot-reduce; agg half of x -> LDS bf16.
// Phase B: A-fragments (16 K-chunks of 32) in registers.
// Phase C: 16 output-tiles; B tile (16KB) staged in LDS for all 4 waves;
//          relu + Wout-dot epilogue; butterfly reduce; atomic segment-sum.

__global__ __launch_bounds__(256, 2)
void fused_main(const float* __restrict__ indiv,
                const float* __restrict__ hier,
                const float* __restrict__ stren,
                const float* __restrict__ rec,
                const int*   __restrict__ sid,
                const float* __restrict__ w1,
                const __bf16* __restrict__ Bp,
                const float* __restrict__ b3,
                const float* __restrict__ wout,
                float* __restrict__ sums,
                float* __restrict__ counts) {
  // agg half of x: per wave 16 members x 256 bf16, stride padded to 264
  // (stride 264*2B = 528B = 33*16B: 16B-aligned, conflict-balanced for b128 reads)
  __shared__ __bf16 xhi[4][16][264];
  __shared__ v8bf  btile[16 * 64];   // 16 KB B tile for current output-tile

  const int tid = threadIdx.x;
  const int w = tid >> 6, L = tid & 63;
  const int mbase = blockIdx.x * 64 + w * 16;

  const float4 w1a = *(const float4*)(w1 + 4 * L);        // weights for H (first 256)
  const float4 w1b = *(const float4*)(w1 + 256 + 4 * L);  // weights for S/R/H (last 256)

  // ---- phase A ----
  const float* hrow = hier  + (size_t)mbase * CFD + 4 * L;
  const float* srow = stren + (size_t)mbase * CFD + 4 * L;
  const float* rrow = rec   + (size_t)mbase * CFD + 4 * L;
  float4 Hc = *(const float4*)hrow;
  float4 Sc = *(const float4*)srow;
  float4 Rc = *(const float4*)rrow;
  for (int i = 0; i < 16; ++i) {
    const int nx = (i < 15) ? (i + 1) : 15;   // prefetch next member
    float4 Hn = *(const float4*)(hrow + nx * CFD);
    float4 Sn = *(const float4*)(srow + nx * CFD);
    float4 Rn = *(const float4*)(rrow + nx * CFD);

    const float pHa = w1a.x*Hc.x + w1a.y*Hc.y + w1a.z*Hc.z + w1a.w*Hc.w;
    const float pSb = w1b.x*Sc.x + w1b.y*Sc.y + w1b.z*Sc.z + w1b.w*Sc.w;
    const float pRb = w1b.x*Rc.x + w1b.y*Rc.y + w1b.z*Rc.z + w1b.w*Rc.w;
    const float pHb = w1b.x*Hc.x + w1b.y*Hc.y + w1b.z*Hc.z + w1b.w*Hc.w;
    float q1 = pHa + pSb;   // e(H,S) pre-act
    float q2 = pHa + pRb;   // e(H,R)
    float q3 = pHa + pHb;   // e(H,H)
#pragma unroll
    for (int m = 32; m; m >>= 1) {
      q1 += __shfl_xor(q1, m, 64);
      q2 += __shfl_xor(q2, m, 64);
      q3 += __shfl_xor(q3, m, 64);
    }
    const float e1 = q1 > 0.f ? q1 : 0.01f * q1;
    const float e2 = q2 > 0.f ? q2 : 0.01f * q2;
    const float e3 = q3 > 0.f ? q3 : 0.01f * q3;
    const float mx = fmaxf(e1, fmaxf(e2, e3));
    float a1 = __expf(e1 - mx), a2 = __expf(e2 - mx), a3 = __expf(e3 - mx);
    const float inv = 1.f / (a1 + a2 + a3);
    a1 *= inv; a2 *= inv; a3 *= inv;

    v4bf g;
    g[0] = (__bf16)(a1 * Sc.x + a2 * Rc.x + a3 * Hc.x);
    g[1] = (__bf16)(a1 * Sc.y + a2 * Rc.y + a3 * Hc.y);
    g[2] = (__bf16)(a1 * Sc.z + a2 * Rc.z + a3 * Hc.z);
    g[3] = (__bf16)(a1 * Sc.w + a2 * Rc.w + a3 * Hc.w);
    *(v4bf*)&xhi[w][i][4 * L] = g;

    Hc = Hn; Sc = Sn; Rc = Rn;
  }

  // ---- phase B: A fragments in registers ----
  // lane holds A[m = L&15][k = (L>>4)*8 + j] per 32-wide K chunk
  const int ml = L & 15;
  const int qo = (L >> 4) * 8;
  v8bf af[16];
  {
    const float* ip = indiv + (size_t)(mbase + ml) * CFD;
#pragma unroll
    for (int c = 0; c < 8; ++c) {
      const float4 f0 = *(const float4*)(ip + c * 32 + qo);
      const float4 f1 = *(const float4*)(ip + c * 32 + qo + 4);
      v8bf t;
      t[0] = (__bf16)f0.x; t[1] = (__bf16)f0.y; t[2] = (__bf16)f0.z; t[3] = (__bf16)f0.w;
      t[4] = (__bf16)f1.x; t[5] = (__bf16)f1.y; t[6] = (__bf16)f1.z; t[7] = (__bf16)f1.w;
      af[c] = t;
    }
#pragma unroll
    for (int c = 0; c < 8; ++c)
      af[8 + c] = *(const v8bf*)&xhi[w][ml][c * 32 + qo];
  }

  // ---- phase C: 16 output tiles of 16 ----
  float p0 = 0.f, p1 = 0.f, p2 = 0.f, p3 = 0.f;
  const uint4* bsrc = (const uint4*)Bp;
  uint4* bl = (uint4*)btile;
  for (int nt = 0; nt < 16; ++nt) {
    __syncthreads();                       // protect previous tile's readers
#pragma unroll
    for (int j = 0; j < 4; ++j)
      bl[tid + j * 256] = bsrc[nt * 1024 + tid + j * 256];
    __syncthreads();

    v4f acc = {0.f, 0.f, 0.f, 0.f};
#pragma unroll
    for (int c = 0; c < 16; ++c) {
      const v8bf bf = btile[c * 64 + L];
      acc = __builtin_amdgcn_mfma_f32_16x16x32_bf16(af[c], bf, acc, 0, 0, 0);
    }
    const float b3n = b3[nt * 16 + ml];
    const float wn  = wout[nt * 16 + ml];
    p0 += fmaxf(acc[0] + b3n, 0.f) * wn;
    p1 += fmaxf(acc[1] + b3n, 0.f) * wn;
    p2 += fmaxf(acc[2] + b3n, 0.f) * wn;
    p3 += fmaxf(acc[3] + b3n, 0.f) * wn;
  }

  // reduce across the 16 lanes (same L>>4 group) holding different n columns
#pragma unroll
  for (int m = 8; m; m >>= 1) {
    p0 += __shfl_xor(p0, m, 64);
    p1 += __shfl_xor(p1, m, 64);
    p2 += __shfl_xor(p2, m, 64);
    p3 += __shfl_xor(p3, m, 64);
  }
  // C row m = (L>>4)*4 + r ; writer lanes: r = L&15 in [0,4)
  const int r = ml;
  if (r < 4) {
    const float pv = (r == 0) ? p0 : (r == 1) ? p1 : (r == 2) ? p2 : p3;
    const int mem = mbase + (L >> 4) * 4 + r;
    const int s = sid[mem];
    atomicAdd(&sums[s], pv);
    atomicAdd(&counts[s], 1.0f);
  }
}

__global__ void finalize_k(const float* __restrict__ sums,
                           const float* __restrict__ counts,
                           const float* __restrict__ bout,
                           float* __restrict__ out) {
  const int s = blockIdx.x * 256 + threadIdx.x;
  if (s < NSEA) out[s] = sums[s] / fmaxf(counts[s], 1.0f) + bout[0];
}

// ---------------- launch ----------------

extern "C" void kernel_launch(void* const* d_in, const int* in_sizes, int n_in,
                              void* d_out, int out_size, void* d_ws, size_t ws_size,
                              hipStream_t stream) {
  (void)in_sizes; (void)n_in; (void)out_size; (void)ws_size;
  const float* indiv = (const float*)d_in[0];
  const float* hier  = (const float*)d_in[1];
  const float* stren = (const float*)d_in[2];
  const float* rec   = (const float*)d_in[3];
  const int*   sid   = (const int*)d_in[4];
  const float* w1    = (const float*)d_in[5];
  // d_in[6..9]: Wq,bq,Wk,bk — dead code (softmax over size-1 axis == 1)
  const float* Wv    = (const float*)d_in[10];
  const float* bv    = (const float*)d_in[11];
  const float* Wo    = (const float*)d_in[12];
  const float* bo    = (const float*)d_in[13];
  const float* Wfc   = (const float*)d_in[14];
  const float* bfc   = (const float*)d_in[15];
  const float* wout  = (const float*)d_in[16];
  const float* bout  = (const float*)d_in[17];
  float* out = (float*)d_out;

  char* ws = (char*)d_ws;
  float*  T1   = (float*)(ws + 0);
  float*  W3   = (float*)(ws + 1048576);
  float*  bc   = (float*)(ws + 1572864);
  float*  b3   = (float*)(ws + 1574912);
  __bf16* Bp   = (__bf16*)(ws + 1575936);
  float*  sums = (float*)(ws + 1838080);
  float*  cnts = (float*)(ws + 1870848);

  hipMemsetAsync(ws + 1838080, 0, 65536, stream);   // sums + counts

  dim3 b16(16, 16);
  gemm_nn<<<dim3(32, 32), b16, 0, stream>>>(Wo,  Wv, T1, 512, 512, 512);
  bias_dot<<<512, 64, 0, stream>>>(Wo, bv, bo, bc, 512);
  gemm_nn<<<dim3(32, 16), b16, 0, stream>>>(Wfc, T1, W3, 256, 512, 512);
  bias_dot<<<256, 64, 0, stream>>>(Wfc, bc, bfc, b3, 512);
  pack_b<<<64, 256, 0, stream>>>(W3, Bp);

  fused_main<<<NMEM / 64, 256, 0, stream>>>(indiv, hier, stren, rec, sid, w1,
                                            Bp, b3, wout, sums, cnts);
  finalize_k<<<NSEA / 256, 256, 0, stream>>>(sums, cnts, bout, out);
}